// Round 2
// baseline (19773.709 us; speedup 1.0000x reference)
//
#include <hip/hip_runtime.h>

#define HID 32
#define NSTEPS 64

// LDS layout (floats): w1[96] | b1[32] | w2[1024] | b2[32] | w3t[96] | b3[3]
// All offsets 16B-aligned so float4 reads emit ds_read_b128 (broadcast: all
// lanes read the same address -> conflict-free, LDS pipe overlaps VALU).
#define OFF_W1 0
#define OFF_B1 96
#define OFF_W2 128
#define OFF_B2 1152
#define OFF_W3 1184
#define OFF_B3 1280
#define SMEM_FLOATS 1284

// Two-row tiny-MLP eval: each weight float4 read from LDS feeds 2*4 FMAs.
__device__ __forceinline__ void mlp2(
    const float4* __restrict__ sw1, const float4* __restrict__ sb1,
    const float4* __restrict__ sw2, const float4* __restrict__ sb2,
    const float4* __restrict__ sw3, const float* __restrict__ sb3,
    float aA0, float aA1, float aA2,
    float aB0, float aB1, float aB2,
    float* __restrict__ kA, float* __restrict__ kB)
{
    float h1A[HID], h1B[HID];
#pragma unroll
    for (int q = 0; q < 8; ++q) {
        float4 w0 = sw1[q], w1v = sw1[8 + q], w2v = sw1[16 + q], bb = sb1[q];
        const float* w0f = (const float*)&w0;
        const float* w1f = (const float*)&w1v;
        const float* w2f = (const float*)&w2v;
        const float* bf  = (const float*)&bb;
#pragma unroll
        for (int e = 0; e < 4; ++e) {
            float vA = fmaf(aA2, w2f[e], fmaf(aA1, w1f[e], fmaf(aA0, w0f[e], bf[e])));
            float vB = fmaf(aB2, w2f[e], fmaf(aB1, w1f[e], fmaf(aB0, w0f[e], bf[e])));
            h1A[q * 4 + e] = fmaxf(vA, 0.0f);
            h1B[q * 4 + e] = fmaxf(vB, 0.0f);
        }
    }

    float h2A[HID], h2B[HID];
#pragma unroll
    for (int q = 0; q < 8; ++q) {
        float4 bb = sb2[q];
        const float* bf = (const float*)&bb;
#pragma unroll
        for (int e = 0; e < 4; ++e) { h2A[q * 4 + e] = bf[e]; h2B[q * 4 + e] = bf[e]; }
    }
#pragma unroll
    for (int i = 0; i < HID; ++i) {
        float hA = h1A[i], hB = h1B[i];
#pragma unroll
        for (int q = 0; q < 8; ++q) {
            float4 w = sw2[i * 8 + q];
            const float* wf = (const float*)&w;
#pragma unroll
            for (int e = 0; e < 4; ++e) {
                h2A[q * 4 + e] = fmaf(hA, wf[e], h2A[q * 4 + e]);
                h2B[q * 4 + e] = fmaf(hB, wf[e], h2B[q * 4 + e]);
            }
        }
    }

#pragma unroll
    for (int i = 0; i < HID; ++i) {
        h2A[i] = fmaxf(h2A[i], 0.0f);
        h2B[i] = fmaxf(h2B[i], 0.0f);
    }
#pragma unroll
    for (int d = 0; d < 3; ++d) {
        float accA = sb3[d], accB = sb3[d];
#pragma unroll
        for (int q = 0; q < 8; ++q) {
            float4 w = sw3[d * 8 + q];
            const float* wf = (const float*)&w;
#pragma unroll
            for (int e = 0; e < 4; ++e) {
                accA = fmaf(h2A[q * 4 + e], wf[e], accA);
                accB = fmaf(h2B[q * 4 + e], wf[e], accB);
            }
        }
        kA[d] = accA; kB[d] = accB;
    }
}

__global__ __launch_bounds__(256, 1)
void ode_rk4_kernel(const float* __restrict__ x,
                    const float* __restrict__ samples,
                    const float* __restrict__ w1, const float* __restrict__ b1,
                    const float* __restrict__ w2, const float* __restrict__ b2,
                    const float* __restrict__ w3, const float* __restrict__ b3,
                    const float* __restrict__ w_out, const float* __restrict__ b_out,
                    float* __restrict__ out, int B)
{
    __shared__ __align__(16) float smem[SMEM_FLOATS];
    const int tid = threadIdx.x;
    for (int i = tid; i < 96; i += 256)   smem[OFF_W1 + i] = w1[i];
    for (int i = tid; i < 32; i += 256)   smem[OFF_B1 + i] = b1[i];
    for (int i = tid; i < 1024; i += 256) smem[OFF_W2 + i] = w2[i];
    for (int i = tid; i < 32; i += 256)   smem[OFF_B2 + i] = b2[i];
    // w3 stored transposed: w3t[d][i] = w3[i][d] so each output dim reads 8 float4s
    for (int i = tid; i < 96; i += 256)   smem[OFF_W3 + (i % 3) * 32 + (i / 3)] = w3[i];
    if (tid < 3) smem[OFF_B3 + tid] = b3[tid];
    __syncthreads();

    const float4* sw1 = (const float4*)(smem + OFF_W1);
    const float4* sb1 = (const float4*)(smem + OFF_B1);
    const float4* sw2 = (const float4*)(smem + OFF_W2);
    const float4* sb2 = (const float4*)(smem + OFF_B2);
    const float4* sw3 = (const float4*)(smem + OFF_W3);
    const float*  sb3 = smem + OFF_B3;

    const int half = B >> 1;
    const int gid = blockIdx.x * blockDim.x + tid;
    if (gid >= half) return;
    const int r0 = gid;
    const int r1 = gid + half;   // two coalesced row streams per wave

    const float maxT = samples[7];
    const float dt   = maxT / 64.0f;
    const float dt2  = 0.5f * dt;
    const float dt6  = dt / 6.0f;

    int sidx[8];
#pragma unroll
    for (int j = 0; j < 8; ++j) {
        int id = (int)rintf(samples[j] / dt) - 1;   // jnp.round = round-half-even
        id = id < 0 ? 0 : (id > NSTEPS - 1 ? NSTEPS - 1 : id);
        sidx[j] = id;
    }

    const float wo0 = w_out[0], wo1 = w_out[1], wo2 = w_out[2];
    const float bo  = b_out[0];

    float yA0 = x[(size_t)r0 * 3 + 0], yA1 = x[(size_t)r0 * 3 + 1], yA2 = x[(size_t)r0 * 3 + 2];
    float yB0 = x[(size_t)r1 * 3 + 0], yB1 = x[(size_t)r1 * 3 + 1], yB2 = x[(size_t)r1 * 3 + 2];

#pragma unroll 1
    for (int s = 0; s < NSTEPS; ++s) {
        float accA0 = 0.0f, accA1 = 0.0f, accA2 = 0.0f;
        float accB0 = 0.0f, accB1 = 0.0f, accB2 = 0.0f;
        float aA0 = yA0, aA1 = yA1, aA2 = yA2;
        float aB0 = yB0, aB1 = yB1, aB2 = yB2;
        // RK4 stage loop kept rolled: hot body is ONE mlp2 (~22 KB, fits I$)
#pragma unroll 1
        for (int st = 0; st < 4; ++st) {
            float kA[3], kB[3];
            mlp2(sw1, sb1, sw2, sb2, sw3, sb3,
                 aA0, aA1, aA2, aB0, aB1, aB2, kA, kB);
            const float ca = (st == 1 || st == 2) ? 2.0f : 1.0f;
            accA0 = fmaf(ca, kA[0], accA0); accA1 = fmaf(ca, kA[1], accA1); accA2 = fmaf(ca, kA[2], accA2);
            accB0 = fmaf(ca, kB[0], accB0); accB1 = fmaf(ca, kB[1], accB1); accB2 = fmaf(ca, kB[2], accB2);
            const float ci = (st == 2) ? dt : dt2;
            aA0 = fmaf(ci, kA[0], yA0); aA1 = fmaf(ci, kA[1], yA1); aA2 = fmaf(ci, kA[2], yA2);
            aB0 = fmaf(ci, kB[0], yB0); aB1 = fmaf(ci, kB[1], yB1); aB2 = fmaf(ci, kB[2], yB2);
        }
        yA0 = fmaf(dt6, accA0, yA0); yA1 = fmaf(dt6, accA1, yA1); yA2 = fmaf(dt6, accA2, yA2);
        yB0 = fmaf(dt6, accB0, yB0); yB1 = fmaf(dt6, accB1, yB1); yB2 = fmaf(dt6, accB2, yB2);

#pragma unroll
        for (int j = 0; j < 8; ++j) {
            if (sidx[j] == s) {
                out[(size_t)j * B + r0] = fmaf(yA2, wo2, fmaf(yA1, wo1, fmaf(yA0, wo0, bo)));
                out[(size_t)j * B + r1] = fmaf(yB2, wo2, fmaf(yB1, wo1, fmaf(yB0, wo0, bo)));
            }
        }
    }
}

extern "C" void kernel_launch(void* const* d_in, const int* in_sizes, int n_in,
                              void* d_out, int out_size, void* d_ws, size_t ws_size,
                              hipStream_t stream) {
    const float* x       = (const float*)d_in[0];
    const float* samples = (const float*)d_in[1];
    const float* w1      = (const float*)d_in[2];
    const float* b1      = (const float*)d_in[3];
    const float* w2      = (const float*)d_in[4];
    const float* b2      = (const float*)d_in[5];
    const float* w3      = (const float*)d_in[6];
    const float* b3      = (const float*)d_in[7];
    const float* w_out   = (const float*)d_in[8];
    const float* b_out   = (const float*)d_in[9];
    float* out = (float*)d_out;

    const int B = in_sizes[0] / 3;
    const int threads = B / 2;
    const int block = 256;
    const int grid = (threads + block - 1) / block;
    ode_rk4_kernel<<<grid, block, 0, stream>>>(
        x, samples, w1, b1, w2, b2, w3, b3, w_out, b_out, out, B);
}

// Round 3
// 3067.655 us; speedup vs baseline: 6.4459x; 6.4459x over previous
//
#include <hip/hip_runtime.h>

#define HID 32
#define NSTEPS 64

// LDS layout (floats): w1[3][32] | b1[32] | w2[32][32] | b2[32] | w3t[3][32] | b3[4]
#define OFF_W1 0
#define OFF_B1 96
#define OFF_W2 128
#define OFF_B2 1152
#define OFF_W3T 1184
#define OFF_B3 1280
#define SMEM_FLOATS 1284

__global__ __launch_bounds__(256)
void ode_rk4_kernel(const float* __restrict__ x,
                    const float* __restrict__ samples,
                    const float* __restrict__ w1, const float* __restrict__ b1,
                    const float* __restrict__ w2, const float* __restrict__ b2,
                    const float* __restrict__ w3, const float* __restrict__ b3,
                    const float* __restrict__ w_out, const float* __restrict__ b_out,
                    float* __restrict__ out, int B)
{
    __shared__ __align__(16) float sm[SMEM_FLOATS];
    const int tid = threadIdx.x;
    for (int i = tid; i < 96; i += 256)   sm[OFF_W1 + i] = w1[i];
    for (int i = tid; i < 32; i += 256)   sm[OFF_B1 + i] = b1[i];
    for (int i = tid; i < 1024; i += 256) sm[OFF_W2 + i] = w2[i];
    for (int i = tid; i < 32; i += 256)   sm[OFF_B2 + i] = b2[i];
    // w3 transposed: w3t[d][j] = w3[j][d]
    for (int i = tid; i < 96; i += 256)   sm[OFF_W3T + (i % 3) * 32 + (i / 3)] = w3[i];
    if (tid < 3) sm[OFF_B3 + tid] = b3[tid];
    __syncthreads();

    const float4* W1q  = (const float4*)(sm + OFF_W1);    // [3][8] quads
    const float4* B1q  = (const float4*)(sm + OFF_B1);    // [8]
    const float4* W2q  = (const float4*)(sm + OFF_W2);    // [32][8]
    const float4* B2q  = (const float4*)(sm + OFF_B2);    // [8]
    const float4* W3Tq = (const float4*)(sm + OFF_W3T);   // [3][8]
    const float*  B3f  = sm + OFF_B3;

    const int half = B >> 1;
    const int gid = blockIdx.x * blockDim.x + tid;
    if (gid >= half) return;
    const int r0 = gid, r1 = gid + half;   // two coalesced row streams

    const float maxT = samples[7];
    const float dt   = maxT / 64.0f;
    const float dt2  = 0.5f * dt;
    const float dt6  = dt / 6.0f;

    int sidx[8];
#pragma unroll
    for (int j = 0; j < 8; ++j) {
        int id = (int)rintf(samples[j] / dt) - 1;   // jnp.round = round-half-even
        id = id < 0 ? 0 : (id > NSTEPS - 1 ? NSTEPS - 1 : id);
        sidx[j] = id;
    }

    const float wo0 = w_out[0], wo1 = w_out[1], wo2 = w_out[2];
    const float bo  = b_out[0];

    float yA0 = x[(size_t)r0 * 3 + 0], yA1 = x[(size_t)r0 * 3 + 1], yA2 = x[(size_t)r0 * 3 + 2];
    float yB0 = x[(size_t)r1 * 3 + 0], yB1 = x[(size_t)r1 * 3 + 1], yB2 = x[(size_t)r1 * 3 + 2];

#pragma unroll 1
    for (int s = 0; s < NSTEPS; ++s) {
        float accA0 = 0.f, accA1 = 0.f, accA2 = 0.f;
        float accB0 = 0.f, accB1 = 0.f, accB2 = 0.f;
        float aA0 = yA0, aA1 = yA1, aA2 = yA2;
        float aB0 = yB0, aB1 = yB1, aB2 = yB2;

#pragma unroll 1
        for (int st = 0; st < 4; ++st) {
            // ---- layer 1: h1 = relu(a @ W1 + b1), both rows ----
            float h1A[HID], h1B[HID];
#pragma unroll
            for (int q = 0; q < 8; ++q) {
                float4 wa = W1q[q], wb = W1q[8 + q], wc = W1q[16 + q], bb = B1q[q];
                h1A[4*q+0] = fmaxf(fmaf(aA2, wc.x, fmaf(aA1, wb.x, fmaf(aA0, wa.x, bb.x))), 0.f);
                h1A[4*q+1] = fmaxf(fmaf(aA2, wc.y, fmaf(aA1, wb.y, fmaf(aA0, wa.y, bb.y))), 0.f);
                h1A[4*q+2] = fmaxf(fmaf(aA2, wc.z, fmaf(aA1, wb.z, fmaf(aA0, wa.z, bb.z))), 0.f);
                h1A[4*q+3] = fmaxf(fmaf(aA2, wc.w, fmaf(aA1, wb.w, fmaf(aA0, wa.w, bb.w))), 0.f);
                h1B[4*q+0] = fmaxf(fmaf(aB2, wc.x, fmaf(aB1, wb.x, fmaf(aB0, wa.x, bb.x))), 0.f);
                h1B[4*q+1] = fmaxf(fmaf(aB2, wc.y, fmaf(aB1, wb.y, fmaf(aB0, wa.y, bb.y))), 0.f);
                h1B[4*q+2] = fmaxf(fmaf(aB2, wc.z, fmaf(aB1, wb.z, fmaf(aB0, wa.z, bb.z))), 0.f);
                h1B[4*q+3] = fmaxf(fmaf(aB2, wc.w, fmaf(aB1, wb.w, fmaf(aB0, wa.w, bb.w))), 0.f);
            }

            // ---- layers 2+3 fused by 8-column blocks: live set stays tiny ----
            float kA0 = B3f[0], kA1 = B3f[1], kA2 = B3f[2];
            float kB0 = B3f[0], kB1 = B3f[1], kB2 = B3f[2];
#pragma unroll 1
            for (int jb = 0; jb < 4; ++jb) {
                float4 b2a = B2q[jb*2], b2b = B2q[jb*2+1];
                float hA[8] = {b2a.x, b2a.y, b2a.z, b2a.w, b2b.x, b2b.y, b2b.z, b2b.w};
                float hB[8] = {b2a.x, b2a.y, b2a.z, b2a.w, b2b.x, b2b.y, b2b.z, b2b.w};
#pragma unroll
                for (int i = 0; i < HID; ++i) {
                    float4 w0 = W2q[i*8 + jb*2], w4 = W2q[i*8 + jb*2 + 1];
                    float vA = h1A[i], vB = h1B[i];
                    hA[0] = fmaf(vA, w0.x, hA[0]); hA[1] = fmaf(vA, w0.y, hA[1]);
                    hA[2] = fmaf(vA, w0.z, hA[2]); hA[3] = fmaf(vA, w0.w, hA[3]);
                    hA[4] = fmaf(vA, w4.x, hA[4]); hA[5] = fmaf(vA, w4.y, hA[5]);
                    hA[6] = fmaf(vA, w4.z, hA[6]); hA[7] = fmaf(vA, w4.w, hA[7]);
                    hB[0] = fmaf(vB, w0.x, hB[0]); hB[1] = fmaf(vB, w0.y, hB[1]);
                    hB[2] = fmaf(vB, w0.z, hB[2]); hB[3] = fmaf(vB, w0.w, hB[3]);
                    hB[4] = fmaf(vB, w4.x, hB[4]); hB[5] = fmaf(vB, w4.y, hB[5]);
                    hB[6] = fmaf(vB, w4.z, hB[6]); hB[7] = fmaf(vB, w4.w, hB[7]);
                }
#pragma unroll
                for (int e = 0; e < 8; ++e) { hA[e] = fmaxf(hA[e], 0.f); hB[e] = fmaxf(hB[e], 0.f); }
                // layer 3 partial: k[d] += h2r[blk] . w3t[d][blk]
#pragma unroll
                for (int d = 0; d < 3; ++d) {
                    float4 t0 = W3Tq[d*8 + jb*2], t4 = W3Tq[d*8 + jb*2 + 1];
                    float sA = fmaf(hA[0], t0.x, fmaf(hA[1], t0.y, fmaf(hA[2], t0.z, hA[3]*t0.w)));
                    sA = fmaf(hA[4], t4.x, fmaf(hA[5], t4.y, fmaf(hA[6], t4.z, fmaf(hA[7], t4.w, sA))));
                    float sB = fmaf(hB[0], t0.x, fmaf(hB[1], t0.y, fmaf(hB[2], t0.z, hB[3]*t0.w)));
                    sB = fmaf(hB[4], t4.x, fmaf(hB[5], t4.y, fmaf(hB[6], t4.z, fmaf(hB[7], t4.w, sB))));
                    if (d == 0) { kA0 += sA; kB0 += sB; }
                    else if (d == 1) { kA1 += sA; kB1 += sB; }
                    else { kA2 += sA; kB2 += sB; }
                }
            }

            const float ca = (st == 1 || st == 2) ? 2.0f : 1.0f;
            accA0 = fmaf(ca, kA0, accA0); accA1 = fmaf(ca, kA1, accA1); accA2 = fmaf(ca, kA2, accA2);
            accB0 = fmaf(ca, kB0, accB0); accB1 = fmaf(ca, kB1, accB1); accB2 = fmaf(ca, kB2, accB2);
            const float ci = (st == 2) ? dt : dt2;
            aA0 = fmaf(ci, kA0, yA0); aA1 = fmaf(ci, kA1, yA1); aA2 = fmaf(ci, kA2, yA2);
            aB0 = fmaf(ci, kB0, yB0); aB1 = fmaf(ci, kB1, yB1); aB2 = fmaf(ci, kB2, yB2);
        }
        yA0 = fmaf(dt6, accA0, yA0); yA1 = fmaf(dt6, accA1, yA1); yA2 = fmaf(dt6, accA2, yA2);
        yB0 = fmaf(dt6, accB0, yB0); yB1 = fmaf(dt6, accB1, yB1); yB2 = fmaf(dt6, accB2, yB2);

#pragma unroll
        for (int j = 0; j < 8; ++j) {
            if (sidx[j] == s) {
                out[(size_t)j * B + r0] = fmaf(yA2, wo2, fmaf(yA1, wo1, fmaf(yA0, wo0, bo)));
                out[(size_t)j * B + r1] = fmaf(yB2, wo2, fmaf(yB1, wo1, fmaf(yB0, wo0, bo)));
            }
        }
    }
}

extern "C" void kernel_launch(void* const* d_in, const int* in_sizes, int n_in,
                              void* d_out, int out_size, void* d_ws, size_t ws_size,
                              hipStream_t stream) {
    const float* x       = (const float*)d_in[0];
    const float* samples = (const float*)d_in[1];
    const float* w1      = (const float*)d_in[2];
    const float* b1      = (const float*)d_in[3];
    const float* w2      = (const float*)d_in[4];
    const float* b2      = (const float*)d_in[5];
    const float* w3      = (const float*)d_in[6];
    const float* b3      = (const float*)d_in[7];
    const float* w_out   = (const float*)d_in[8];
    const float* b_out   = (const float*)d_in[9];
    float* out = (float*)d_out;

    const int B = in_sizes[0] / 3;
    const int threads = B / 2;
    const int block = 256;
    const int grid = (threads + block - 1) / block;
    ode_rk4_kernel<<<grid, block, 0, stream>>>(
        x, samples, w1, b1, w2, b2, w3, b3, w_out, b_out, out, B);
}